// Round 9
// baseline (306.846 us; speedup 1.0000x reference)
//
#include <hip/hip_runtime.h>
#include <cmath>

#define SEQ 32
#define BB 1024
#define II 2048
#define OO 1024

typedef unsigned short ushortt;

// ---- build idx row (ordered) + idxT ushort4 groups [g][b] + rev scatter (rcnt pre-zeroed) ----
// float4 x-reads: 8 global iterations; lane-major ordering reproduces the exact
// ascending-column idxArr of the scalar version.
__global__ void build_idx_rev(const float* __restrict__ x, ushortt* __restrict__ idxArr,
                              int* __restrict__ cntArr, int* __restrict__ rcnt,
                              ushortt* __restrict__ rev, ushortt* __restrict__ idxT) {
  int b = blockIdx.x;
  int lane = threadIdx.x;  // 64 threads = 1 wave
  __shared__ ushortt sIdx[256];
  const float4* row4 = (const float4*)(x + (long)b * II);
  int base = 0;
  for (int c4 = 0; c4 < II / 256; ++c4) {
    float4 v = row4[c4 * 64 + lane];
    unsigned long long m0 = __ballot(v.x != 0.f);
    unsigned long long m1 = __ballot(v.y != 0.f);
    unsigned long long m2 = __ballot(v.z != 0.f);
    unsigned long long m3 = __ballot(v.w != 0.f);
    unsigned long long below = (1ull << lane) - 1ull;
    int pre = __popcll(m0 & below) + __popcll(m1 & below) +
              __popcll(m2 & below) + __popcll(m3 & below);
    int col0 = c4 * 256 + lane * 4;
    int pos = base + pre;
    if (v.x != 0.f) { if (pos < 256) { idxArr[(b << 8) + pos] = (ushortt)col0;       sIdx[pos] = (ushortt)col0; }       ++pos; }
    if (v.y != 0.f) { if (pos < 256) { idxArr[(b << 8) + pos] = (ushortt)(col0 + 1); sIdx[pos] = (ushortt)(col0 + 1); } ++pos; }
    if (v.z != 0.f) { if (pos < 256) { idxArr[(b << 8) + pos] = (ushortt)(col0 + 2); sIdx[pos] = (ushortt)(col0 + 2); } ++pos; }
    if (v.w != 0.f) { if (pos < 256) { idxArr[(b << 8) + pos] = (ushortt)(col0 + 3); sIdx[pos] = (ushortt)(col0 + 3); } ++pos; }
    base += __popcll(m0) + __popcll(m1) + __popcll(m2) + __popcll(m3);
  }
  int cnt = base < 256 ? base : 256;  // uniform across lanes
  if (lane == 0) cntArr[b] = cnt;
  __syncthreads();
  {
    int j0 = lane * 4;
    ushort4 u;
    u.x = (j0 + 0 < cnt) ? sIdx[j0 + 0] : (ushortt)II;
    u.y = (j0 + 1 < cnt) ? sIdx[j0 + 1] : (ushortt)II;
    u.z = (j0 + 2 < cnt) ? sIdx[j0 + 2] : (ushortt)II;
    u.w = (j0 + 3 < cnt) ? sIdx[j0 + 3] : (ushortt)II;
    ((ushort4*)idxT)[(lane << 10) + b] = u;
  }
  for (int j = lane; j < cnt; j += 64) {
    int i = sIdx[j];
    int pos = atomicAdd(&rcnt[i], 1);
    if (pos < 128) rev[((long)i << 7) + pos] = (ushortt)b;
  }
}

// ---------------- dual transpose for z/v ([O][B] -> [B][O]) ----------------
__global__ void transpose2_f32(const float* __restrict__ zC, const float* __restrict__ vC,
                               float* __restrict__ oz, float* __restrict__ ov) {
  __shared__ float t[32][33];
  const float* src = blockIdx.z ? vC : zC;
  float* dst = blockIdx.z ? ov : oz;
  int c0 = blockIdx.x * 32, r0 = blockIdx.y * 32;  // src is OO x BB
  int tx = threadIdx.x, ty = threadIdx.y;
#pragma unroll
  for (int k = 0; k < 4; k++)
    t[ty + k * 8][tx] = src[(long)(r0 + ty + k * 8) * BB + c0 + tx];
  __syncthreads();
#pragma unroll
  for (int k = 0; k < 4; k++)
    dst[(long)(c0 + ty + k * 8) * OO + r0 + tx] = t[tx][ty + k * 8];
}

// ---------------- full 32-step sim, one block per column ----------------
// FULLY INCREMENTAL spike step: instead of re-gathering wL+aG (2 LDS words per
// active element), the per-element dw is affine in (mt, n, A), so S/SA update
// from aggregates. The only gather is ONE word: mL[i] = ±(mt+1) (sign = old
// clip status; +1 bias so sign survives mt==0 without signed-zero tricks),
// giving G = sum mt, GC = sum_clip mt, cC = |clip ∩ act|. Clip/unclip flips
// and rare high-clips scatter exact per-event corrections over rev[i].
// Snu stays integer-exact via flip scatters (proven). wL/aG never gathered.
// LDS 38.9 KB -> 4 blocks/CU, 32 waves/CU.
__global__ __launch_bounds__(512, 8) void snn_kernel(
    const float* __restrict__ w, const float* __restrict__ bias,
    const ushortt* __restrict__ idxT, const int* __restrict__ cntArr,
    const int* __restrict__ rcnt, const ushortt* __restrict__ rev,
    const ushortt* __restrict__ idxArr,
    float* __restrict__ zC, float* __restrict__ vC, float* __restrict__ outw,
    float dec) {
  int o = blockIdx.x, tid = threadIdx.x, lane = tid & 63, wave = tid >> 6;
  __shared__ float wL[II + 1];     // live w; pad slot 2048 = 0 (init gather)
  __shared__ float aG[II];         // A, masked 0 when clipped (never gathered)
  __shared__ float mLb[II + 1];    // spike: signed(mt+1), pad=+1; quiet: Sfix lo; init: nT
  __shared__ ushortt sList[BB];    // spike list (values < 1024)
  __shared__ float SnuD[BB];       // flip deltas of Snu (both phases)
  __shared__ float SfxSp[BB];      // spike S corrections (flip fix / unclip dw / high-clip)
  __shared__ float SadSp[BB];      // spike SA deltas; quiet SAD
  __shared__ int sCnt, sFlag, cFlag;
  float* nT = mLb;                 // init-only alias
  float* mL = mLb;
  float* Sfix = mLb;               // quiet-phase alias (lo 1024)
  float* SAD = SadSp;              // quiet-phase alias

#pragma unroll
  for (int q = 0; q < 4; ++q) {
    int i = q * 512 + tid;
    wL[i] = w[(long)o * II + i];
    aG[i] = 0.f;
    nT[i] = (float)rcnt[i];
  }
#pragma unroll
  for (int k = 0; k < 2; ++k) {
    int b = k * 512 + tid;
    SnuD[b] = 0.f; SfxSp[b] = 0.f; SadSp[b] = 0.f;
  }
  if (tid == 0) {
    sFlag = 0; cFlag = 0;
    wL[II] = 0.f; nT[II] = 0.f;
  }

  int jmax[2];
  float cntf[2];
#pragma unroll
  for (int k = 0; k < 2; ++k) {
    int c = cntArr[k * 512 + tid];
    cntf[k] = (float)c;
#pragma unroll
    for (int off = 32; off > 0; off >>= 1) c = max(c, __shfl_xor(c, off));
    jmax[k] = c;
  }
  float bo = bias[o];
  unsigned clipped = 0;
  bool everSpk = false;
  float p = 1.f, u = 1.f;
  __syncthreads();

  // initial gather: S = sum w (double, ascending order), Snu = N_b = sum n
  const ushort4* tpb = (const ushort4*)idxT;
  double S[2];
  float Snu[2], Nb[2], SA[2], v4[2], zk[2];
#pragma unroll
  for (int k = 0; k < 2; ++k) {
    int b = k * 512 + tid;
    double s = 0.0;
    float sn = 0.f;
    int jm4 = (jmax[k] + 3) >> 2;
    const ushort4* tp = tpb + b;
    for (int g = 0; g < jm4; ++g) {
      ushort4 u0 = tp[(g << 10)];
      s += (double)wL[u0.x]; sn += nT[u0.x];
      s += (double)wL[u0.y]; sn += nT[u0.y];
      s += (double)wL[u0.z]; sn += nT[u0.z];
      s += (double)wL[u0.w]; sn += nT[u0.w];
    }
    S[k] = s; Snu[k] = sn; Nb[k] = sn;
    SA[k] = 0.f; v4[k] = 0.f; zk[k] = 0.f;
  }
  __syncthreads();  // nT reads done; region becomes Sfix/mL
  Sfix[tid] = 0.f; Sfix[512 + tid] = 0.f;

  for (int t = 0; t < SEQ; ++t) {
    p *= dec; u *= dec; u += 1.f;
    float spre = u - p;
    // phase A: z/v from S
    int local = 0;
#pragma unroll
    for (int k = 0; k < 2; ++k) {
      float zin = (float)S[k] + bo;
      float nv = v4[k] * dec + zin;
      float z = (nv >= 1.f) ? 1.f : 0.f;
      nv = nv * (1.f - z);
      v4[k] = nv; zk[k] = z;
      if (z != 0.f) local = 1;
    }
    if (local) sFlag = 1;
    __syncthreads();
    int spk = sFlag;

    if (!spk) {
      // quiet step: per-i recurrence + wave-cooperative clip scatter (as R6)
#pragma unroll
      for (int q = 0; q < 4; ++q) {
        int i = q * 512 + tid;
        bool already = (clipped >> q) & 1u;
        float n = 0.f, atn = 0.f, fix = 0.f;
        bool cl = false;
        if (!already) {
          n = (float)rcnt[i];
          atn = everSpk ? (dec * aG[i]) : 0.f;
          float dw = -(1e-3f * (p * n + atn));
          float wold = wL[i];
          float pre = wold + dw;
          float wv = fminf(fmaxf(pre, -1.f), 1.f);
          cl = (pre <= -1.f);
          if (cl) {
            clipped |= 1u << q;
            fix = (-1.f - wold) - dw;
            if (everSpk) aG[i] = 0.f;
          } else if (everSpk) {
            aG[i] = atn;
          }
          wL[i] = wv;
        }
        unsigned long long m = __ballot(cl);
        if (m) {
          if (lane == 0) cFlag = 1;
          while (m) {
            int src = __builtin_ctzll(m);
            m &= m - 1;
            int ii = __shfl(i, src);
            float fx = __shfl(fix, src);
            float mn = -__shfl(n, src);
            float ma = -__shfl(atn, src);
            int rc = rcnt[ii];
            const ushortt* rp = rev + ((long)ii << 7);
            for (int r = lane; r < rc; r += 64) {
              int b2 = rp[r];
              atomicAdd(&Sfix[b2], fx);
              atomicAdd(&SnuD[b2], mn);
              if (everSpk) atomicAdd(&SAD[b2], ma);
            }
          }
        }
      }
      __syncthreads();
      float coefP = 1e-3f * p;
      if (cFlag) {
#pragma unroll
        for (int k = 0; k < 2; ++k) {
          int b = k * 512 + tid;
          S[k] = S[k] - (double)coefP * (double)Snu[k]
                      - (double)1e-3f * (double)(dec * SA[k])
                      + (double)Sfix[b];
          SA[k] = dec * SA[k] + SAD[b];
          Snu[k] = Snu[k] + SnuD[b];
          Sfix[b] = 0.f; SnuD[b] = 0.f; SAD[b] = 0.f;
        }
      } else {
#pragma unroll
        for (int k = 0; k < 2; ++k) {
          S[k] = S[k] - (double)coefP * (double)Snu[k]
                      - (double)1e-3f * (double)(dec * SA[k]);
          SA[k] = dec * SA[k];
        }
      }
      if (tid == 0) { sFlag = 0; cFlag = 0; }
      __syncthreads();
    } else {
      // spike step (incremental): mL scatter, per-i update + signed write-back,
      // flip/high-clip correction scatters, ONE-word gather, analytic S/SA.
      everSpk = true;
      if (tid == 0) sCnt = 0;
      __syncthreads();
#pragma unroll
      for (int k = 0; k < 2; ++k)
        if (zk[k] != 0.f) { int pos = atomicAdd(&sCnt, 1); sList[pos] = (ushortt)(k * 512 + tid); }
#pragma unroll
      for (int q = 0; q < 4; ++q) mL[q * 512 + tid] = 0.f;
      if (tid == 0) mLb[II] = 1.0f;  // pad decodes as mt=0, non-clipped
      __syncthreads();
      int ns = sCnt;
      for (int s = wave; s < ns; s += 8) {
        int b = sList[s];
        int cbb = cntArr[b];
        const ushortt* ip = idxArr + (b << 8);
        for (int j = lane; j < cbb; j += 64)
          atomicAdd(&mL[ip[j]], 1.f);
      }
      __syncthreads();
      float cv = (float)ns;
#pragma unroll
      for (int q = 0; q < 4; ++q) {
        int i = q * 512 + tid;
        float mt = mL[i];
        float atn = dec * aG[i] + mt;
        float n = (float)rcnt[i];
        float dw = 1e-3f * (p * cv + spre * mt) - 1e-3f * (p * n + atn);
        float wold = wL[i];
        float pre = wold + dw;
        float wv = fminf(fmaxf(pre, -1.f), 1.f);
        bool cl = (pre <= -1.f);
        bool was = (clipped >> q) & 1u;
        if (cl) clipped |= 1u << q; else clipped &= ~(1u << q);
        wL[i] = wv;
        aG[i] = cl ? 0.f : atn;
        mL[i] = was ? -(mt + 1.f) : (mt + 1.f);  // signed write-back for gather
        bool hic = (pre >= 1.f);                  // high clip (w saturates at +1)
        bool flip = (cl != was);
        float dS = cl ? ((-1.f - wold) - dw) : dw;  // clip-flip fix | unclip +dw
        float dn = cl ? -n : n;                      // Snu delta
        float dsa = cl ? -atn : mt;                  // SA delta
        unsigned long long m = __ballot(flip);
        while (m) {
          int src = __builtin_ctzll(m);
          m &= m - 1;
          int ii = __shfl(i, src);
          float a1 = __shfl(dS, src);
          float a2 = __shfl(dn, src);
          float a3 = __shfl(dsa, src);
          int rc = rcnt[ii];
          const ushortt* rp = rev + ((long)ii << 7);
          for (int r = lane; r < rc; r += 64) {
            int b2 = rp[r];
            atomicAdd(&SfxSp[b2], a1);
            atomicAdd(&SnuD[b2], a2);
            atomicAdd(&SadSp[b2], a3);
          }
        }
        unsigned long long mh = __ballot(hic);
        while (mh) {
          int src = __builtin_ctzll(mh);
          mh &= mh - 1;
          int ii = __shfl(i, src);
          float a1 = 1.f - __shfl(pre, src);
          int rc = rcnt[ii];
          const ushortt* rp = rev + ((long)ii << 7);
          for (int r = lane; r < rc; r += 64)
            atomicAdd(&SfxSp[rp[r]], a1);
        }
      }
      __syncthreads();  // mL signed + scatters complete
      // ONE-word gather: G = sum mt, GC = sum over old-clipped, cC = count
#pragma unroll
      for (int k = 0; k < 2; ++k) {
        int b = k * 512 + tid;
        float G = 0.f, GC = 0.f, cC = 0.f;
        int jm4 = (jmax[k] + 3) >> 2;
        const ushort4* tp = tpb + b;
        for (int g = 0; g < jm4; ++g) {
          ushort4 u0 = tp[(g << 10)];
          float e0 = mL[u0.x], e1 = mL[u0.y], e2 = mL[u0.z], e3 = mL[u0.w];
          float a0 = fabsf(e0) - 1.f, a1 = fabsf(e1) - 1.f;
          float a2 = fabsf(e2) - 1.f, a3 = fabsf(e3) - 1.f;
          G += a0 + a1 + a2 + a3;
          if (e0 < 0.f) { GC += a0; cC += 1.f; }
          if (e1 < 0.f) { GC += a1; cC += 1.f; }
          if (e2 < 0.f) { GC += a2; cC += 1.f; }
          if (e3 < 0.f) { GC += a3; cC += 1.f; }
        }
        float NC = Nb[k] - Snu[k];
        float d_all = 1e-3f * (p * cv * cntf[k] + spre * G)
                    - 1e-3f * (p * Nb[k] + dec * SA[k] + G);
        float d_cor = -1e-3f * (p * cv * cC + spre * GC)
                    + 1e-3f * (p * NC + GC);
        S[k] = S[k] + (double)d_all + (double)d_cor + (double)SfxSp[b];
        SA[k] = dec * SA[k] + (G - GC) + SadSp[b];
        Snu[k] = Snu[k] + SnuD[b];
        SfxSp[b] = 0.f; SadSp[b] = 0.f; SnuD[b] = 0.f;
      }
      __syncthreads();  // all gathers done before mLb-lo is re-purposed
      Sfix[tid] = 0.f; Sfix[512 + tid] = 0.f;  // restore quiet-phase invariant
      if (tid == 0) { sFlag = 0; cFlag = 0; }
      __syncthreads();
    }
  }

  __syncthreads();
  // coalesced outputs: w row-major; z/v column-major staging (transposed after)
#pragma unroll
  for (int q = 0; q < 4; ++q) outw[(long)o * II + q * 512 + tid] = wL[q * 512 + tid];
#pragma unroll
  for (int k = 0; k < 2; ++k) {
    int b = k * 512 + tid;
    zC[(long)o * BB + b] = zk[k];
    vC[(long)o * BB + b] = v4[k];
  }
}

extern "C" void kernel_launch(void* const* d_in, const int* in_sizes, int n_in,
                              void* d_out, int out_size, void* d_ws, size_t ws_size,
                              hipStream_t stream) {
  const float* x = (const float*)d_in[0];     // [B, I] {0,1} fp32
  const float* w = (const float*)d_in[1];     // [O, I] fp32
  const float* bias = (const float*)d_in[2];  // [O]
  float* out = (float*)d_out;                 // z[B,O] | v[B,O] | w[O,I]

  char* ws = (char*)d_ws;
  ushortt* idxArr = (ushortt*)(ws + 0);        // 512 KB
  int* cntArr = (int*)(ws + 524288);           // 4 KB
  ushortt* idxT = (ushortt*)(ws + 528384);     // 512 KB + 8 KB pad
  int* rcnt = (int*)(ws + 1060864);            // 8 KB
  ushortt* rev = (ushortt*)(ws + 1069056);     // 512 KB
  float* zC = (float*)(ws + 1593344);          // 4 MB
  float* vC = (float*)(ws + 5787648);          // 4 MB

  hipMemsetAsync(rcnt, 0, II * sizeof(int), stream);
  build_idx_rev<<<BB, 64, 0, stream>>>(x, idxArr, cntArr, rcnt, rev, idxT);

  const float dec = (float)exp(-0.05);  // shared decay (pre/post/mem)

  snn_kernel<<<OO, 512, 0, stream>>>(w, bias, idxT, cntArr, rcnt, rev, idxArr,
                                     zC, vC, out + 2 * BB * OO, dec);

  // z, v: [O][B] -> [B][O]
  transpose2_f32<<<dim3(BB / 32, OO / 32, 2), dim3(32, 8), 0, stream>>>(zC, vC, out, out + BB * OO);
}

// Round 10
// 276.216 us; speedup vs baseline: 1.1109x; 1.1109x over previous
//
#include <hip/hip_runtime.h>
#include <cmath>

#define SEQ 32
#define BB 1024
#define II 2048
#define OO 1024

typedef unsigned short ushortt;

// ---- build idx row (ordered) + idxT ushort4 groups [g][b] + rev scatter (rcnt pre-zeroed) ----
// float4 x-reads: 8 global iterations; lane-major ordering reproduces the exact
// ascending-column idxArr of the scalar version. (R8, proven)
__global__ void build_idx_rev(const float* __restrict__ x, ushortt* __restrict__ idxArr,
                              int* __restrict__ cntArr, int* __restrict__ rcnt,
                              ushortt* __restrict__ rev, ushortt* __restrict__ idxT) {
  int b = blockIdx.x;
  int lane = threadIdx.x;  // 64 threads = 1 wave
  __shared__ ushortt sIdx[256];
  const float4* row4 = (const float4*)(x + (long)b * II);
  int base = 0;
  for (int c4 = 0; c4 < II / 256; ++c4) {
    float4 v = row4[c4 * 64 + lane];
    unsigned long long m0 = __ballot(v.x != 0.f);
    unsigned long long m1 = __ballot(v.y != 0.f);
    unsigned long long m2 = __ballot(v.z != 0.f);
    unsigned long long m3 = __ballot(v.w != 0.f);
    unsigned long long below = (1ull << lane) - 1ull;
    int pre = __popcll(m0 & below) + __popcll(m1 & below) +
              __popcll(m2 & below) + __popcll(m3 & below);
    int col0 = c4 * 256 + lane * 4;
    int pos = base + pre;
    if (v.x != 0.f) { if (pos < 256) { idxArr[(b << 8) + pos] = (ushortt)col0;       sIdx[pos] = (ushortt)col0; }       ++pos; }
    if (v.y != 0.f) { if (pos < 256) { idxArr[(b << 8) + pos] = (ushortt)(col0 + 1); sIdx[pos] = (ushortt)(col0 + 1); } ++pos; }
    if (v.z != 0.f) { if (pos < 256) { idxArr[(b << 8) + pos] = (ushortt)(col0 + 2); sIdx[pos] = (ushortt)(col0 + 2); } ++pos; }
    if (v.w != 0.f) { if (pos < 256) { idxArr[(b << 8) + pos] = (ushortt)(col0 + 3); sIdx[pos] = (ushortt)(col0 + 3); } ++pos; }
    base += __popcll(m0) + __popcll(m1) + __popcll(m2) + __popcll(m3);
  }
  int cnt = base < 256 ? base : 256;  // uniform across lanes
  if (lane == 0) cntArr[b] = cnt;
  __syncthreads();
  {
    int j0 = lane * 4;
    ushort4 u;
    u.x = (j0 + 0 < cnt) ? sIdx[j0 + 0] : (ushortt)II;
    u.y = (j0 + 1 < cnt) ? sIdx[j0 + 1] : (ushortt)II;
    u.z = (j0 + 2 < cnt) ? sIdx[j0 + 2] : (ushortt)II;
    u.w = (j0 + 3 < cnt) ? sIdx[j0 + 3] : (ushortt)II;
    ((ushort4*)idxT)[(lane << 10) + b] = u;
  }
  for (int j = lane; j < cnt; j += 64) {
    int i = sIdx[j];
    int pos = atomicAdd(&rcnt[i], 1);
    if (pos < 128) rev[((long)i << 7) + pos] = (ushortt)b;
  }
}

// ---------------- dual transpose for z/v ([O][B] -> [B][O]) ----------------
__global__ void transpose2_f32(const float* __restrict__ zC, const float* __restrict__ vC,
                               float* __restrict__ oz, float* __restrict__ ov) {
  __shared__ float t[32][33];
  const float* src = blockIdx.z ? vC : zC;
  float* dst = blockIdx.z ? ov : oz;
  int c0 = blockIdx.x * 32, r0 = blockIdx.y * 32;  // src is OO x BB
  int tx = threadIdx.x, ty = threadIdx.y;
#pragma unroll
  for (int k = 0; k < 4; k++)
    t[ty + k * 8][tx] = src[(long)(r0 + ty + k * 8) * BB + c0 + tx];
  __syncthreads();
#pragma unroll
  for (int k = 0; k < 4; k++)
    dst[(long)(c0 + ty + k * 8) * OO + r0 + tx] = t[tx][ty + k * 8];
}

// ---------------- full 32-step sim, one block per column ----------------
// R6 verbatim: best measured snn variant (193.6 us). Separate fp32 wL/aG
// arrays (b32 gathers; b64/float2 packing measured slower twice, incremental
// spike step measured slower). Snu maintained by integer-exact flip scatters;
// nG deleted (n from L2-hot rcnt). Spike re-gather reads 2 words/element.
// LDS ~32.8 KB -> 4 blocks/CU, 32 waves/CU.
__global__ __launch_bounds__(512, 8) void snn_kernel(
    const float* __restrict__ w, const float* __restrict__ bias,
    const ushortt* __restrict__ idxT, const int* __restrict__ cntArr,
    const int* __restrict__ rcnt, const ushortt* __restrict__ rev,
    const ushortt* __restrict__ idxArr,
    float* __restrict__ zC, float* __restrict__ vC, float* __restrict__ outw,
    float dec) {
  int o = blockIdx.x, tid = threadIdx.x, lane = tid & 63, wave = tid >> 6;
  __shared__ float shbuf[8195];
  __shared__ int sCnt, sFlag, cFlag;
  float* wL = shbuf;                    // [0..2048] live w (pad slot 2048 = 0)
  float* aG = shbuf + 2049;             // [0..2048] A, masked 0 when clipped
  float* mL = shbuf + 4098;             // [0..2048] spike counts; slot 2048 = init-nT pad
  int* sList = (int*)(shbuf + 6147);    // 1024 (spike phase)
  float* SnuD = shbuf + 7171;           // 1024 DEDICATED (both phases; flip deltas)
  float* nT = shbuf + 4098;             // init staging of rcnt (aliases mL, init only)
  float* Sfix = shbuf + 4098;           // 1024 (quiet phase, aliases mL lo)
  float* SAD = (float*)(shbuf + 6147);  // 1024 (quiet phase, aliases sList)

#pragma unroll
  for (int q = 0; q < 4; ++q) {
    int i = q * 512 + tid;
    wL[i] = w[(long)o * II + i];
    aG[i] = 0.f;
    nT[i] = (float)rcnt[i];
  }
#pragma unroll
  for (int k = 0; k < 2; ++k) SnuD[k * 512 + tid] = 0.f;
  if (tid == 0) {
    sFlag = 0; cFlag = 0;
    wL[II] = 0.f; aG[II] = 0.f; nT[II] = 0.f;
  }

  int jmax[2];
#pragma unroll
  for (int k = 0; k < 2; ++k) {
    int c = cntArr[k * 512 + wave * 64 + lane];
#pragma unroll
    for (int off = 32; off > 0; off >>= 1) c = max(c, __shfl_xor(c, off));
    jmax[k] = c;
  }
  float bo = bias[o];
  unsigned clipped = 0;
  bool everSpk = false;
  float p = 1.f, u = 1.f;
  __syncthreads();

  // initial gather: S = sum w, Snu = sum n over act(b) (nothing clipped yet)
  const ushort4* tpb = (const ushort4*)idxT;
  double S[2];
  float Snu[2], SA[2], v4[2], zk[2];
#pragma unroll
  for (int k = 0; k < 2; ++k) {
    int b = k * 512 + tid;
    double s = 0.0;
    float sn = 0.f;
    int jm4 = (jmax[k] + 3) >> 2;
    const ushort4* tp = tpb + b;
    for (int g = 0; g < jm4; ++g) {
      ushort4 u0 = tp[(g << 10)];
      int a_ = u0.x, b_ = u0.y, c_ = u0.z, d_ = u0.w;
      s += (double)wL[a_]; sn += nT[a_];
      s += (double)wL[b_]; sn += nT[b_];
      s += (double)wL[c_]; sn += nT[c_];
      s += (double)wL[d_]; sn += nT[d_];
    }
    S[k] = s; Snu[k] = sn;
    SA[k] = 0.f; v4[k] = 0.f; zk[k] = 0.f;
  }
  __syncthreads();  // nT reads done; region becomes Sfix/mL
#pragma unroll
  for (int k = 0; k < 2; ++k) {
    int b = k * 512 + tid;
    Sfix[b] = 0.f; SAD[b] = 0.f;
  }

  for (int t = 0; t < SEQ; ++t) {
    p *= dec; u *= dec; u += 1.f;
    float spre = u - p;
    // phase A: z/v from S
    int local = 0;
#pragma unroll
    for (int k = 0; k < 2; ++k) {
      float zin = (float)S[k] + bo;
      float nv = v4[k] * dec + zin;
      float z = (nv >= 1.f) ? 1.f : 0.f;
      nv = nv * (1.f - z);
      v4[k] = nv; zk[k] = z;
      if (z != 0.f) local = 1;
    }
    if (local) sFlag = 1;
    __syncthreads();
    int spk = sFlag;

    if (!spk) {
      // quiet step: per-i recurrence + wave-cooperative clip scatter
#pragma unroll
      for (int q = 0; q < 4; ++q) {
        int i = q * 512 + tid;
        bool already = (clipped >> q) & 1u;
        float n = 0.f, atn = 0.f, fix = 0.f;
        bool cl = false;
        if (!already) {
          n = (float)rcnt[i];
          atn = everSpk ? (dec * aG[i]) : 0.f;
          float dw = -(1e-3f * (p * n + atn));
          float wold = wL[i];
          float pre = wold + dw;
          float wv = fminf(fmaxf(pre, -1.f), 1.f);
          cl = (pre <= -1.f);
          if (cl) {
            clipped |= 1u << q;
            fix = (-1.f - wold) - dw;
            if (everSpk) aG[i] = 0.f;
          } else if (everSpk) {
            aG[i] = atn;
          }
          wL[i] = wv;
        }
        unsigned long long m = __ballot(cl);
        if (m) {
          if (lane == 0) cFlag = 1;
          while (m) {
            int src = __builtin_ctzll(m);
            m &= m - 1;
            int ii = __shfl(i, src);
            float fx = __shfl(fix, src);
            float mn = -__shfl(n, src);
            float ma = -__shfl(atn, src);
            int rc = rcnt[ii];
            const ushortt* rp = rev + ((long)ii << 7);
            for (int r = lane; r < rc; r += 64) {
              int b2 = rp[r];
              atomicAdd(&Sfix[b2], fx);
              atomicAdd(&SnuD[b2], mn);
              if (everSpk) atomicAdd(&SAD[b2], ma);
            }
          }
        }
      }
      __syncthreads();
      float coefP = 1e-3f * p;
      if (cFlag) {
#pragma unroll
        for (int k = 0; k < 2; ++k) {
          int b = k * 512 + tid;
          S[k] = S[k] - (double)coefP * (double)Snu[k]
                      - (double)1e-3f * (double)(dec * SA[k])
                      + (double)Sfix[b];
          SA[k] = dec * SA[k] + SAD[b];
          Snu[k] = Snu[k] + SnuD[b];
          Sfix[b] = 0.f; SnuD[b] = 0.f; SAD[b] = 0.f;
        }
      } else {
#pragma unroll
        for (int k = 0; k < 2; ++k) {
          S[k] = S[k] - (double)coefP * (double)Snu[k]
                      - (double)1e-3f * (double)(dec * SA[k]);
          SA[k] = dec * SA[k];
        }
      }
      if (tid == 0) { sFlag = 0; cFlag = 0; }
      __syncthreads();
    } else {
      // spike step: per-i update via mL; Snu via flip scatters; re-gather (w,A)
      everSpk = true;
      if (tid == 0) sCnt = 0;
      __syncthreads();
#pragma unroll
      for (int k = 0; k < 2; ++k)
        if (zk[k] != 0.f) { int pos = atomicAdd(&sCnt, 1); sList[pos] = k * 512 + tid; }
#pragma unroll
      for (int q = 0; q < 4; ++q) mL[q * 512 + tid] = 0.f;
      __syncthreads();
      int ns = sCnt;
      // sparse scatter: mL[i] += 1 over active index list of each spiking batch
      for (int s = wave; s < ns; s += 8) {
        int b = sList[s];
        int cbb = cntArr[b];
        const ushortt* ip = idxArr + (b << 8);
        for (int j = lane; j < cbb; j += 64)
          atomicAdd(&mL[ip[j]], 1.f);
      }
      __syncthreads();
      float cv = (float)ns;
#pragma unroll
      for (int q = 0; q < 4; ++q) {
        int i = q * 512 + tid;
        float mt = mL[i];
        float atn = dec * aG[i] + mt;
        float n = (float)rcnt[i];  // true n
        float dw = 1e-3f * (p * cv + spre * mt) - 1e-3f * (p * n + atn);
        float wold = wL[i];
        float pre = wold + dw;
        float wv = fminf(fmaxf(pre, -1.f), 1.f);
        bool cl = (pre <= -1.f);
        bool was = (clipped >> q) & 1u;
        if (cl) clipped |= 1u << q; else clipped &= ~(1u << q);
        wL[i] = wv;
        aG[i] = cl ? 0.f : atn;
        // Snu flip scatter: masked-n aggregate changes only on status flips
        bool flip = (cl != was);
        float dn = cl ? -n : n;
        unsigned long long m = __ballot(flip);
        while (m) {
          int src = __builtin_ctzll(m);
          m &= m - 1;
          int ii = __shfl(i, src);
          float d = __shfl(dn, src);
          int rc = rcnt[ii];
          const ushortt* rp = rev + ((long)ii << 7);
          for (int r = lane; r < rc; r += 64)
            atomicAdd(&SnuD[rp[r]], d);
        }
      }
      __syncthreads();  // wL/aG final, SnuD deltas complete; mL/sList dead
      // re-gather S (double, ascending-j order) and SA via ushort4 idxT groups
#pragma unroll
      for (int k = 0; k < 2; ++k) {
        int b = k * 512 + tid;
        double s = 0.0;
        float sa = 0.f;
        int jm4 = (jmax[k] + 3) >> 2;
        const ushort4* tp = tpb + b;
        for (int g = 0; g < jm4; ++g) {
          ushort4 u0 = tp[(g << 10)];
          int a_ = u0.x, b_ = u0.y, c_ = u0.z, d_ = u0.w;
          s += (double)wL[a_]; sa += aG[a_];
          s += (double)wL[b_]; sa += aG[b_];
          s += (double)wL[c_]; sa += aG[c_];
          s += (double)wL[d_]; sa += aG[d_];
        }
        S[k] = s; SA[k] = sa;
        Snu[k] = Snu[k] + SnuD[b];
        SnuD[b] = 0.f;
        Sfix[b] = 0.f; SAD[b] = 0.f;  // restore quiet-phase invariant
      }
      if (tid == 0) { sFlag = 0; cFlag = 0; }
      __syncthreads();
    }
  }

  __syncthreads();
  // coalesced outputs: w row-major; z/v column-major staging (transposed after)
#pragma unroll
  for (int q = 0; q < 4; ++q) outw[(long)o * II + q * 512 + tid] = wL[q * 512 + tid];
#pragma unroll
  for (int k = 0; k < 2; ++k) {
    int b = k * 512 + tid;
    zC[(long)o * BB + b] = zk[k];
    vC[(long)o * BB + b] = v4[k];
  }
}

extern "C" void kernel_launch(void* const* d_in, const int* in_sizes, int n_in,
                              void* d_out, int out_size, void* d_ws, size_t ws_size,
                              hipStream_t stream) {
  const float* x = (const float*)d_in[0];     // [B, I] {0,1} fp32
  const float* w = (const float*)d_in[1];     // [O, I] fp32
  const float* bias = (const float*)d_in[2];  // [O]
  float* out = (float*)d_out;                 // z[B,O] | v[B,O] | w[O,I]

  char* ws = (char*)d_ws;
  ushortt* idxArr = (ushortt*)(ws + 0);        // 512 KB
  int* cntArr = (int*)(ws + 524288);           // 4 KB
  ushortt* idxT = (ushortt*)(ws + 528384);     // 512 KB + 8 KB pad
  int* rcnt = (int*)(ws + 1060864);            // 8 KB
  ushortt* rev = (ushortt*)(ws + 1069056);     // 512 KB
  float* zC = (float*)(ws + 1593344);          // 4 MB
  float* vC = (float*)(ws + 5787648);          // 4 MB

  hipMemsetAsync(rcnt, 0, II * sizeof(int), stream);
  build_idx_rev<<<BB, 64, 0, stream>>>(x, idxArr, cntArr, rcnt, rev, idxT);

  const float dec = (float)exp(-0.05);  // shared decay (pre/post/mem)

  snn_kernel<<<OO, 512, 0, stream>>>(w, bias, idxT, cntArr, rcnt, rev, idxArr,
                                     zC, vC, out + 2 * BB * OO, dec);

  // z, v: [O][B] -> [B][O]
  transpose2_f32<<<dim3(BB / 32, OO / 32, 2), dim3(32, 8), 0, stream>>>(zC, vC, out, out + BB * OO);
}